// Round 7
// baseline (24550.308 us; speedup 1.0000x reference)
//
#include <hip/hip_runtime.h>

namespace {
constexpr int B = 128;      // batch
constexpr int D = 80;       // mel dim
constexpr int H = 256;      // hidden
constexpr int PP = 128;     // prenet out
constexpr int TIN = 512;    // encoder steps
constexpr int RSTEPS = 200; // reduced steps
constexpr int RF = 5;       // reduction factor
}

__device__ __forceinline__ float sigm(float x) { return 1.f / (1.f + __expf(-x)); }
__device__ __forceinline__ float tanh_(float x) { return 1.f - 2.f / (__expf(2.f * x) + 1.f); }
__device__ __forceinline__ float dot4(float4 a, float4 b) {
  return a.x * b.x + a.y * b.y + a.z * b.z + a.w * b.w;
}
__device__ __forceinline__ unsigned short f2bf(float f) {  // RNE
  unsigned int u = __float_as_uint(f);
  u += 0x7fffu + ((u >> 16) & 1u);
  return (unsigned short)(u >> 16);
}
__device__ __forceinline__ void bf2x(unsigned int w, float& f0, float& f1) {
  f0 = __uint_as_float(w << 16);
  f1 = __uint_as_float(w & 0xffff0000u);
}
__device__ __forceinline__ void unpack8(uint4 w, float* f) {
  bf2x(w.x, f[0], f[1]); bf2x(w.y, f[2], f[3]);
  bf2x(w.z, f[4], f[5]); bf2x(w.w, f[6], f[7]);
}

// ---------------------------------------------------------------------------
// keysB[b,t,k] = bf16( sum_h memory[t,b,h] * Wm[h,k] )
__global__ __launch_bounds__(256) void k_keys(const float* __restrict__ mem,
                                              const float* __restrict__ Wm,
                                              unsigned short* __restrict__ keysB) {
  const int k = threadIdx.x;
  const int m0 = blockIdx.x * 32;
  const float* xb = mem + (size_t)m0 * H;
  float acc[32];
#pragma unroll
  for (int i = 0; i < 32; ++i) acc[i] = 0.f;
  for (int h = 0; h < H; h += 4) {
    const float w0 = Wm[(h + 0) * H + k];
    const float w1 = Wm[(h + 1) * H + k];
    const float w2 = Wm[(h + 2) * H + k];
    const float w3 = Wm[(h + 3) * H + k];
#pragma unroll
    for (int mi = 0; mi < 32; ++mi) {
      const float4 x = *reinterpret_cast<const float4*>(xb + (size_t)mi * H + h);
      acc[mi] += x.x * w0 + x.y * w1 + x.z * w2 + x.w * w3;
    }
  }
#pragma unroll
  for (int mi = 0; mi < 32; ++mi) {
    const int m = m0 + mi, t = m >> 7, bb = m & 127;
    keysB[((size_t)bb * TIN + t) * H + k] = f2bf(acc[mi]);
  }
}

// memB[b,t,h] = bf16(memory[t,b,h])
__global__ __launch_bounds__(256) void k_memB(const float* __restrict__ mem,
                                              unsigned short* __restrict__ memB) {
  const int m = blockIdx.x, t = m >> 7, bb = m & 127;
  memB[((size_t)bb * TIN + t) * H + threadIdx.x] = f2bf(mem[(size_t)m * H + threadIdx.x]);
}

// pack W[K][C] -> Wp[(k>>2)*C + c][k&3]  (float4 of 4 consecutive k per col)
__global__ __launch_bounds__(256) void k_pack4(const float* __restrict__ W,
                                               float* __restrict__ Wp, int K, int C) {
  const int idx = blockIdx.x * 256 + threadIdx.x;
  if (idx >= K * C) return;
  const int k = idx / C, c = idx - k * C;
  Wp[((size_t)(k >> 2) * C + c) * 4 + (k & 3)] = W[idx];
}

// pack Wq[256][256] -> bf16 [(k>>3)*256 + c]*8 + (k&7)
__global__ __launch_bounds__(256) void k_packWq(const float* __restrict__ W,
                                                unsigned short* __restrict__ Wp) {
  const int idx = blockIdx.x * 256 + threadIdx.x;
  const int k = idx >> 8, c = idx & 255;
  Wp[(((size_t)(k >> 3) * 256) + c) * 8 + (k & 7)] = f2bf(W[idx]);
}

// ---------------------------------------------------------------------------
// Hoisted prenet (teacher-forced frames come from INPUT outs).
__global__ __launch_bounds__(256) void k_prenet(
    const float* __restrict__ outs, const float* __restrict__ Wp0,
    const float* __restrict__ bp0, const float* __restrict__ Wp1,
    const float* __restrict__ bp1, float* __restrict__ pre) {
  const int t = blockIdx.x >> 7, b = blockIdx.x & 127, tid = threadIdx.x;
  __shared__ float f[80];
  __shared__ float p0[256];
  __shared__ float s2[256];
  if (tid < 80)
    f[tid] = (t == 0) ? 0.f
                      : __builtin_nontemporal_load(
                            &outs[((size_t)(t * RF - 1) * B + b) * D + tid]);
  __syncthreads();
  {
    float a = bp0[tid];
#pragma unroll 8
    for (int k = 0; k < 80; ++k) a += f[k] * Wp0[k * 256 + tid];
    p0[tid] = fmaxf(a, 0.f);
  }
  __syncthreads();
  {
    const int c = tid & 127, kh = tid >> 7;
    float a = 0.f;
#pragma unroll 8
    for (int k = kh * 128; k < kh * 128 + 128; ++k) a += p0[k] * Wp1[k * 128 + c];
    s2[kh * 128 + c] = a;
  }
  __syncthreads();
  if (tid < 128)
    pre[((size_t)t * B + b) * PP + tid] = fmaxf(bp1[tid] + s2[tid] + s2[128 + tid], 0.f);
}

// ---------------------------------------------------------------------------
// Persistent per-batch-row block; bf16 streams, packed-weight GEMVs.
__global__ __launch_bounds__(1024, 4) void k_step(
    const unsigned short* __restrict__ memB, const unsigned short* __restrict__ keysB,
    const float* __restrict__ pre,
    const float* __restrict__ wxa4, const float* __restrict__ wha4,
    const float* __restrict__ b_att, const unsigned short* __restrict__ wqB,
    const float* __restrict__ v_att,
    const float* __restrict__ wxd04, const float* __restrict__ whd04,
    const float* __restrict__ b_d0,
    const float* __restrict__ wxd14, const float* __restrict__ whd14,
    const float* __restrict__ b_d1,
    const float* __restrict__ Wo, const float* __restrict__ bo,
    float* __restrict__ dout, float* __restrict__ alpha) {
  const int b = blockIdx.x;
  const int tid = threadIdx.x;
  const int lane = tid & 63, wv = tid >> 6;

  __shared__ alignas(16) float hA[256], hD0[256], hD1[256];
  __shared__ alignas(16) float qk_l[256], ctx_l[256], res0_l[256], res1_l[256];
  __shared__ alignas(16) float pre_l[128];
  __shared__ alignas(16) float v_l[256];
  __shared__ alignas(16) float scr[8192];
  __shared__ alignas(16) float ep[512];
  __shared__ float r16[16];
  __shared__ float bc[2];

  if (tid < 256) { hA[tid] = 0.f; hD0[tid] = 0.f; hD1[tid] = 0.f; v_l[tid] = v_att[tid]; }
  __syncthreads();

  const float4* hA4 = reinterpret_cast<const float4*>(hA);
  const float4* hD04 = reinterpret_cast<const float4*>(hD0);
  const float4* hD14 = reinterpret_cast<const float4*>(hD1);
  const float4* ctx4 = reinterpret_cast<const float4*>(ctx_l);
  const float4* res04 = reinterpret_cast<const float4*>(res0_l);
  const float4* pre4 = reinterpret_cast<const float4*>(pre_l);

  for (int t = 0; t < RSTEPS; ++t) {
    if (tid < PP) pre_l[tid] = pre[((size_t)t * B + b) * PP + tid];
    __syncthreads();

    // ---- attention GRU: x-part (K=128) + h-part (K=256), packed float4 ----
    {
      const int j = tid & 255, ks = tid >> 8;
      float pz = 0, pr = 0, px = 0, ph = 0;
#pragma unroll 4
      for (int kq = ks * 8; kq < ks * 8 + 8; ++kq) {
        const float4 xv = pre4[kq];
        const float4* wr = reinterpret_cast<const float4*>(wxa4) + (size_t)kq * 768;
        pz += dot4(wr[j], xv); pr += dot4(wr[256 + j], xv); px += dot4(wr[512 + j], xv);
      }
#pragma unroll 4
      for (int kq = ks * 16; kq < ks * 16 + 16; ++kq) {
        const float4 hv = hA4[kq];
        const float4* wr = reinterpret_cast<const float4*>(wha4) + (size_t)kq * 768;
        pz += dot4(wr[j], hv); pr += dot4(wr[256 + j], hv); ph += dot4(wr[512 + j], hv);
      }
      scr[ks * 1024 + j] = pz;       scr[ks * 1024 + 256 + j] = pr;
      scr[ks * 1024 + 512 + j] = px; scr[ks * 1024 + 768 + j] = ph;
    }
    __syncthreads();
    if (tid < 256) {
      float az = 0, ar = 0, acx = 0, ach = 0;
#pragma unroll
      for (int ks = 0; ks < 4; ++ks) {
        az += scr[ks * 1024 + tid];        ar += scr[ks * 1024 + 256 + tid];
        acx += scr[ks * 1024 + 512 + tid]; ach += scr[ks * 1024 + 768 + tid];
      }
      const float z = sigm(az + b_att[tid]);
      const float r = sigm(ar + b_att[256 + tid]);
      const float c = tanh_(acx + r * ach + b_att[512 + tid]);
      hA[tid] = (1.f - z) * hA[tid] + z * c;   // = query
    }
    __syncthreads();

    // ---- qW (K=256, 256 cols, bf16-packed 8/k-group) ----
    {
      const int c = tid & 255, ks = tid >> 8;
      float a = 0.f;
      const uint4* wB = reinterpret_cast<const uint4*>(wqB);
#pragma unroll 4
      for (int kq8 = ks * 8; kq8 < ks * 8 + 8; ++kq8) {
        const uint4 w = wB[(size_t)kq8 * 256 + c];
        const float4 h0 = hA4[kq8 * 2], h1 = hA4[kq8 * 2 + 1];
        float w0, w1;
        bf2x(w.x, w0, w1); a += w0 * h0.x + w1 * h0.y;
        bf2x(w.y, w0, w1); a += w0 * h0.z + w1 * h0.w;
        bf2x(w.z, w0, w1); a += w0 * h1.x + w1 * h1.y;
        bf2x(w.w, w0, w1); a += w0 * h1.z + w1 * h1.w;
      }
      scr[ks * 256 + c] = a;
    }
    __syncthreads();
    if (tid < 256)
      qk_l[tid] = scr[tid] + scr[256 + tid] + scr[512 + tid] + scr[768 + tid];
    __syncthreads();

    // ---- e-pass: 64 groups x 16 lanes, bf16 keys (2 uint4 per t-row) ----
    {
      const int l16 = tid & 15, g = tid >> 4;
      float qg[16], vg[16];
#pragma unroll
      for (int i = 0; i < 16; ++i) { qg[i] = qk_l[l16 * 16 + i]; vg[i] = v_l[l16 * 16 + i]; }
      const uint4* kB = reinterpret_cast<const uint4*>(keysB + (size_t)b * TIN * H);
#pragma unroll
      for (int p = 0; p < 4; ++p) {
        const int t1 = g + p * 128, t2 = t1 + 64;
        const uint4 a0 = kB[t1 * 32 + l16 * 2], a1 = kB[t1 * 32 + l16 * 2 + 1];
        const uint4 b0 = kB[t2 * 32 + l16 * 2], b1 = kB[t2 * 32 + l16 * 2 + 1];
        float ka[16], kb2[16];
        unpack8(a0, ka); unpack8(a1, ka + 8);
        unpack8(b0, kb2); unpack8(b1, kb2 + 8);
        float s1 = 0.f, s2 = 0.f;
#pragma unroll
        for (int i = 0; i < 16; ++i) {
          s1 += vg[i] * tanh_(ka[i] + qg[i]);
          s2 += vg[i] * tanh_(kb2[i] + qg[i]);
        }
#pragma unroll
        for (int m = 1; m < 16; m <<= 1) { s1 += __shfl_xor(s1, m, 16); s2 += __shfl_xor(s2, m, 16); }
        if (l16 == 0) { ep[t1] = s1; ep[t2] = s2; }
      }
    }
    __syncthreads();

    // ---- softmax over 512 ----
    float ev = -1e30f, pv = 0.f;
    if (tid < TIN) {
      ev = ep[tid];
      float mx = ev;
#pragma unroll
      for (int m = 1; m < 64; m <<= 1) mx = fmaxf(mx, __shfl_xor(mx, m));
      if (lane == 0) r16[wv] = mx;
    }
    __syncthreads();
    if (tid == 0) {
      float g = r16[0];
#pragma unroll
      for (int w = 1; w < 8; ++w) g = fmaxf(g, r16[w]);
      bc[0] = g;
    }
    __syncthreads();
    const float M = bc[0];
    if (tid < TIN) {
      pv = __expf(ev - M);
      ep[tid] = pv;
      float s = pv;
#pragma unroll
      for (int m = 1; m < 64; m <<= 1) s += __shfl_xor(s, m);
      if (lane == 0) r16[wv] = s;
    }
    __syncthreads();
    if (tid == 0) {
      float s = 0.f;
#pragma unroll
      for (int w = 0; w < 8; ++w) s += r16[w];
      bc[1] = 1.f / s;
    }
    __syncthreads();
    const float inv = bc[1];
    if (tid < TIN)
      __builtin_nontemporal_store(pv * inv, &alpha[((size_t)t * B + b) * TIN + tid]);

    // ---- context: bf16 memB; thread = (8 k's, 16 t's); 32-slice reduce ----
    {
      const int kq8 = tid & 31, ts = tid >> 5;
      float a[8] = {0.f, 0.f, 0.f, 0.f, 0.f, 0.f, 0.f, 0.f};
      const uint4* mB = reinterpret_cast<const uint4*>(memB + (size_t)b * TIN * H);
#pragma unroll 4
      for (int i = 0; i < 16; ++i) {
        const int tt = ts * 16 + i;
        const float p = ep[tt];
        float mv[8];
        unpack8(mB[tt * 32 + kq8], mv);
#pragma unroll
        for (int j = 0; j < 8; ++j) a[j] += p * mv[j];
      }
      float4* s4 = reinterpret_cast<float4*>(scr + ts * 256 + kq8 * 8);
      s4[0] = make_float4(a[0], a[1], a[2], a[3]);
      s4[1] = make_float4(a[4], a[5], a[6], a[7]);
    }
    __syncthreads();
    if (tid < 256) {
      float s = 0.f;
#pragma unroll
      for (int ts2 = 0; ts2 < 32; ++ts2) s += scr[ts2 * 256 + tid];
      ctx_l[tid] = inv * s;
    }
    __syncthreads();

    // ---- decoder GRU 0: x=[query;ctx] (K=512) + h (K=256), packed ----
    {
      const int j = tid & 255, ks = tid >> 8;
      float pz = 0, pr = 0, px = 0, ph = 0;
#pragma unroll 4
      for (int kq = ks * 32; kq < ks * 32 + 32; ++kq) {
        const float4 xv = (kq < 64) ? hA4[kq] : ctx4[kq - 64];
        const float4* wr = reinterpret_cast<const float4*>(wxd04) + (size_t)kq * 768;
        pz += dot4(wr[j], xv); pr += dot4(wr[256 + j], xv); px += dot4(wr[512 + j], xv);
      }
#pragma unroll 4
      for (int kq = ks * 16; kq < ks * 16 + 16; ++kq) {
        const float4 hv = hD04[kq];
        const float4* wr = reinterpret_cast<const float4*>(whd04) + (size_t)kq * 768;
        pz += dot4(wr[j], hv); pr += dot4(wr[256 + j], hv); ph += dot4(wr[512 + j], hv);
      }
      scr[ks * 1024 + j] = pz;       scr[ks * 1024 + 256 + j] = pr;
      scr[ks * 1024 + 512 + j] = px; scr[ks * 1024 + 768 + j] = ph;
    }
    __syncthreads();
    if (tid < 256) {
      float az = 0, ar = 0, acx = 0, ach = 0;
#pragma unroll
      for (int ks = 0; ks < 4; ++ks) {
        az += scr[ks * 1024 + tid];        ar += scr[ks * 1024 + 256 + tid];
        acx += scr[ks * 1024 + 512 + tid]; ach += scr[ks * 1024 + 768 + tid];
      }
      const float z = sigm(az + b_d0[tid]);
      const float r = sigm(ar + b_d0[256 + tid]);
      const float c = tanh_(acx + r * ach + b_d0[512 + tid]);
      const float hn = (1.f - z) * hD0[tid] + z * c;
      hD0[tid] = hn;
      res0_l[tid] = hA[tid] + hn;
    }
    __syncthreads();

    // ---- decoder GRU 1: x=res0 (K=256) + h (K=256), packed ----
    {
      const int j = tid & 255, ks = tid >> 8;
      float pz = 0, pr = 0, px = 0, ph = 0;
#pragma unroll 4
      for (int kq = ks * 16; kq < ks * 16 + 16; ++kq) {
        const float4 xv = res04[kq];
        const float4* wr = reinterpret_cast<const float4*>(wxd14) + (size_t)kq * 768;
        pz += dot4(wr[j], xv); pr += dot4(wr[256 + j], xv); px += dot4(wr[512 + j], xv);
      }
#pragma unroll 4
      for (int kq = ks * 16; kq < ks * 16 + 16; ++kq) {
        const float4 hv = hD14[kq];
        const float4* wr = reinterpret_cast<const float4*>(whd14) + (size_t)kq * 768;
        pz += dot4(wr[j], hv); pr += dot4(wr[256 + j], hv); ph += dot4(wr[512 + j], hv);
      }
      scr[ks * 1024 + j] = pz;       scr[ks * 1024 + 256 + j] = pr;
      scr[ks * 1024 + 512 + j] = px; scr[ks * 1024 + 768 + j] = ph;
    }
    __syncthreads();
    if (tid < 256) {
      float az = 0, ar = 0, acx = 0, ach = 0;
#pragma unroll
      for (int ks = 0; ks < 4; ++ks) {
        az += scr[ks * 1024 + tid];        ar += scr[ks * 1024 + 256 + tid];
        acx += scr[ks * 1024 + 512 + tid]; ach += scr[ks * 1024 + 768 + tid];
      }
      const float z = sigm(az + b_d1[tid]);
      const float r = sigm(ar + b_d1[256 + tid]);
      const float c = tanh_(acx + r * ach + b_d1[512 + tid]);
      const float hn = (1.f - z) * hD1[tid] + z * c;
      hD1[tid] = hn;
      res1_l[tid] = res0_l[tid] + hn;
    }
    __syncthreads();

    // ---- dense: 80 cols, 8 K-slices -> 5 output frames (NT) ----
    {
      const int c = tid & 127, ks = tid >> 7;
      float a = 0.f;
      if (c < D) {
#pragma unroll 8
        for (int k = ks * 32; k < ks * 32 + 32; ++k) a += res1_l[k] * Wo[k * D + c];
      }
      scr[ks * 128 + c] = a;
    }
    __syncthreads();
    if (tid < D) {
      float dv = bo[tid];
#pragma unroll
      for (int ks = 0; ks < 8; ++ks) dv += scr[ks * 128 + tid];
      const size_t base = (size_t)t * RF * (B * D) + (size_t)b * D + tid;
#pragma unroll
      for (int i = 0; i < RF; ++i)
        __builtin_nontemporal_store(dv, &dout[base + (size_t)i * (B * D)]);
    }
    __syncthreads();
  }
}

// ---------------------------------------------------------------------------
extern "C" void kernel_launch(void* const* d_in, const int* in_sizes, int n_in,
                              void* d_out, int out_size, void* d_ws,
                              size_t ws_size, hipStream_t stream) {
  const float* outs   = (const float*)d_in[0];
  const float* memory = (const float*)d_in[1];
  const float* Wp0    = (const float*)d_in[2];
  const float* bp0    = (const float*)d_in[3];
  const float* Wp1    = (const float*)d_in[4];
  const float* bp1    = (const float*)d_in[5];
  const float* Wx_att = (const float*)d_in[6];
  const float* Wh_att = (const float*)d_in[7];
  const float* b_att  = (const float*)d_in[8];
  const float* Wq     = (const float*)d_in[9];
  const float* Wm     = (const float*)d_in[10];
  const float* v_att  = (const float*)d_in[11];
  const float* Wx_d0  = (const float*)d_in[12];
  const float* Wh_d0  = (const float*)d_in[13];
  const float* b_d0   = (const float*)d_in[14];
  const float* Wx_d1  = (const float*)d_in[15];
  const float* Wh_d1  = (const float*)d_in[16];
  const float* b_d1   = (const float*)d_in[17];
  const float* Wo     = (const float*)d_in[18];
  const float* bo     = (const float*)d_in[19];
  float* dout = (float*)d_out;
  float* wsf  = (float*)d_ws;

  size_t off = 0;
  unsigned short* keysB = (unsigned short*)(wsf + off); off += (size_t)TIN * B * H / 2;
  unsigned short* memB  = (unsigned short*)(wsf + off); off += (size_t)TIN * B * H / 2;
  unsigned short* wqB   = (unsigned short*)(wsf + off); off += (size_t)256 * 256 / 2;
  float* pre   = wsf + off; off += (size_t)RSTEPS * B * PP;
  float* wxa4  = wsf + off; off += (size_t)128 * 768;
  float* wha4  = wsf + off; off += (size_t)256 * 768;
  float* wxd04 = wsf + off; off += (size_t)512 * 768;
  float* whd04 = wsf + off; off += (size_t)256 * 768;
  float* wxd14 = wsf + off; off += (size_t)256 * 768;
  float* whd14 = wsf + off; off += (size_t)256 * 768;

  k_keys<<<(TIN * B) / 32, 256, 0, stream>>>(memory, Wm, keysB);
  k_memB<<<TIN * B, 256, 0, stream>>>(memory, memB);
  k_prenet<<<RSTEPS * B, 256, 0, stream>>>(outs, Wp0, bp0, Wp1, bp1, pre);
  k_packWq<<<256, 256, 0, stream>>>(Wq, wqB);
  k_pack4<<<(128 * 768 + 255) / 256, 256, 0, stream>>>(Wx_att, wxa4, 128, 768);
  k_pack4<<<(256 * 768 + 255) / 256, 256, 0, stream>>>(Wh_att, wha4, 256, 768);
  k_pack4<<<(512 * 768 + 255) / 256, 256, 0, stream>>>(Wx_d0, wxd04, 512, 768);
  k_pack4<<<(256 * 768 + 255) / 256, 256, 0, stream>>>(Wh_d0, whd04, 256, 768);
  k_pack4<<<(256 * 768 + 255) / 256, 256, 0, stream>>>(Wx_d1, wxd14, 256, 768);
  k_pack4<<<(256 * 768 + 255) / 256, 256, 0, stream>>>(Wh_d1, whd14, 256, 768);

  float* alpha = dout + (size_t)1000 * B * D;
  k_step<<<B, 1024, 0, stream>>>(memB, keysB, pre,
                                 wxa4, wha4, b_att, wqB, v_att,
                                 wxd04, whd04, b_d0, wxd14, whd14, b_d1,
                                 Wo, bo, dout, alpha);
}